// Round 5
// baseline (625.459 us; speedup 1.0000x reference)
//
#include <hip/hip_runtime.h>
#include <hip/hip_bf16.h>

// Fused Conv3d(3->16,k=3,valid) + conv_b + ReLU + maxpool2x2x2
// + spatial mean(fp32) + /2 + bias + channel-sum  ->  out[32] fp32.
// Inputs are FLOAT32 (harness materializes reference fp16 as f32).
//
// Two-hop staging to kill the VALU-bound im2col gather:
//   Phase 1: coalesced float4 global loads (3/thread) -> v_cvt_pk_bf16_f32
//            -> raw bf16 LDS tile [3][4dl][4hl][128w] (12,288 B).
//   Phase 2: im2col columns built from raw LDS: 27x ds_read_u16 with
//            all-immediate offsets (2 lanes/dword -> conflict-free),
//            packed to 4x ds_write_b128 into xs[dh][w][tap] (stride 80 B).
//   Phase 3 (verified): mfma_f32_16x16x32_bf16, A=weights(regs),
//            B=im2col cols, kw via 3 shifted MFMAs; D: col=lane&15=w,
//            row=q*4+r=channel. Pool closes in-register; wave-reduce; atomic.

typedef __attribute__((ext_vector_type(8))) short short8;
typedef __attribute__((ext_vector_type(4))) float floatx4;
typedef __attribute__((ext_vector_type(2))) unsigned uint2v;

__device__ __forceinline__ short f2bf(float f) {
    // fp32 -> bf16 bits, RNE (finite inputs); used only for the 24 weight cvts
    unsigned u = __builtin_bit_cast(unsigned, f);
    unsigned r = (u + 0x7FFFu + ((u >> 16) & 1u)) >> 16;
    return (short)r;
}

__device__ __forceinline__ unsigned pkbf2(float a, float b) {
    __hip_bfloat162 h = __float22bfloat162_rn(float2{a, b});  // v_cvt_pk_bf16_f32
    unsigned r;
    __builtin_memcpy(&r, &h, 4);
    return r;
}

#define TAPS_PAD 40   // shorts per im2col column (80 B: 16B-aligned, bank-clean)
#define NCOL 130      // cols 0..127 staged, 128..129 explicitly zeroed

__global__ __launch_bounds__(512) void fused_conv_pool_reduce(
    const float* __restrict__ xg,    // f32 [32][3][32][128][128]
    const float* __restrict__ wg,    // f32 [16][3][3][3][3]
    const float* __restrict__ cbg,   // f32 [16]
    const float* __restrict__ biasg, // f32 [16]
    float* __restrict__ out)         // f32 [32]
{
    __shared__ __align__(16) unsigned rawu[3072];          // bf16 [3][4][4][128], 12,288 B
    __shared__ __align__(16) short xs[4][NCOL][TAPS_PAD];  // 41,600 B
    __shared__ float wsums[8];

    const int hp  = blockIdx.x;   // 0..62
    const int dp  = blockIdx.y;   // 0..14
    const int b   = blockIdx.z;   // 0..31
    const int tid = threadIdx.x;  // 0..511
    const int lane = tid & 63;
    const int wv   = tid >> 6;

    const int m = lane & 15;      // A-operand row (output channel)
    const int q = lane >> 4;      // K-quad

    // ---- A fragments (weights): A[m][k=q*8+j], one per kw ----
    short8 afrag[3];
    #pragma unroll
    for (int kw = 0; kw < 3; ++kw) {
        #pragma unroll
        for (int j = 0; j < 8; ++j) {
            const int k = q * 8 + j;
            afrag[kw][j] = (k < 27) ? f2bf(wg[m * 81 + k * 3 + kw]) : (short)0;
        }
    }

    // ---- zero im2col pad columns 128..129 (read by wave 7's kw shifts) ----
    if (tid < 320) {
        const int dhz = tid / 80;
        const int rem = tid % 80;
        xs[dhz][128 + rem / 40][rem % 40] = 0;
    }

    // ---- phase 1: raw stage, coalesced float4 + packed cvt ----
    {
        const int w4 = tid & 31, hr = (tid >> 5) & 3, dr = (tid >> 7) & 3;
        const float* src = xg + ((size_t)(b * 3) * 32 + 2 * dp + dr) * 16384
                              + (2 * hp + hr) * 128 + w4 * 4;
        const int fo = (dr * 128 + hr * 32 + w4) * 2;   // dword offset within ci slab
        #pragma unroll
        for (int ci = 0; ci < 3; ++ci) {
            const floatx4 v = *(const floatx4*)(src + (size_t)ci * 524288);
            uint2v pk; pk[0] = pkbf2(v[0], v[1]); pk[1] = pkbf2(v[2], v[3]);
            *(uint2v*)&rawu[fo + ci * 1024] = pk;       // ds_write_b64
        }
    }
    __syncthreads();

    // ---- phase 2: im2col column build from raw LDS ----
    {
        const int dhi = tid >> 7;        // 0..3 : dd = dhi>>1, hh = dhi&1
        const int w   = tid & 127;
        const int dd = dhi >> 1, hh = dhi & 1;
        const unsigned short* raws = (const unsigned short*)rawu;
        const unsigned short* base = raws + dd * 512 + hh * 128 + w;
        unsigned short vals[27];
        #pragma unroll
        for (int ci = 0; ci < 3; ++ci)
            #pragma unroll
            for (int kd = 0; kd < 3; ++kd)
                #pragma unroll
                for (int kh = 0; kh < 3; ++kh)
                    vals[ci * 9 + kd * 3 + kh] = base[ci * 2048 + kd * 512 + kh * 128];
        short* col = &xs[dhi][w][0];
        #pragma unroll
        for (int blk = 0; blk < 4; ++blk) {
            short8 pk;
            #pragma unroll
            for (int j = 0; j < 8; ++j) {
                const int t = blk * 8 + j;
                pk[j] = (t < 27) ? (short)vals[t] : (short)0;
            }
            *(short8*)(col + blk * 8) = pk;             // ds_write_b128
        }
    }
    __syncthreads();

    // ---- phase 3: MFMA, wave = one 16-wide w-tile, pool in-register ----
    const int n  = lane & 15;     // w position within tile (N = D col)
    const int w0 = wv * 16;
    floatx4 mx = {-3.0e38f, -3.0e38f, -3.0e38f, -3.0e38f};
    #pragma unroll
    for (int dh = 0; dh < 4; ++dh) {
        floatx4 acc = {0.f, 0.f, 0.f, 0.f};
        #pragma unroll
        for (int kw = 0; kw < 3; ++kw) {
            const short8 bfr = *(const short8*)(&xs[dh][w0 + n + kw][q * 8]);
            acc = __builtin_amdgcn_mfma_f32_16x16x32_bf16(afrag[kw], bfr, acc, 0, 0, 0);
        }
        #pragma unroll
        for (int r = 0; r < 4; ++r) mx[r] = fmaxf(mx[r], acc[r]);  // pool d,h
    }

    // D row (channel) = q*4 + r; relu(max + conv_b[ch]) then w-pair pool
    float vsum = 0.f;
    #pragma unroll
    for (int r = 0; r < 4; ++r) {
        const float cb = cbg[q * 4 + r];
        float v = fmaxf(mx[r] + cb, 0.f);
        float o = __shfl_xor(v, 1, 64);
        vsum += fmaxf(v, o);
    }
    const bool ok = ((lane & 1) == 0) && (w0 + (n & 14) <= 124);  // conv W = 126
    float s = ok ? vsum : 0.f;
    #pragma unroll
    for (int off = 1; off < 64; off <<= 1) s += __shfl_xor(s, off, 64);

    if (lane == 0) wsums[wv] = s;
    __syncthreads();
    if (tid == 0) {
        float bs = 0.f;
        #pragma unroll
        for (int i = 0; i < 8; ++i) bs += wsums[i];
        float add = bs * (1.0f / 119070.0f);   // /(15*63*63)/2
        if (hp == 0 && dp == 0) {              // fold bias-sum init (out memset to 0)
            #pragma unroll
            for (int cc = 0; cc < 16; ++cc) add += biasg[cc];
        }
        atomicAdd(&out[b], add);
    }
}

extern "C" void kernel_launch(void* const* d_in, const int* in_sizes, int n_in,
                              void* d_out, int out_size, void* d_ws, size_t ws_size,
                              hipStream_t stream) {
    const float* x      = (const float*)d_in[0];
    const float* conv_w = (const float*)d_in[1];
    const float* conv_b = (const float*)d_in[2];
    const float* bias   = (const float*)d_in[3];
    float* out = (float*)d_out;

    (void)hipMemsetAsync(out, 0, 32 * sizeof(float), stream);  // graph-capturable
    dim3 grid(63, 15, 32);  // (hp, dp, b)
    fused_conv_pool_reduce<<<grid, 512, 0, stream>>>(x, conv_w, conv_b, bias, out);
}

// Round 6
// 616.903 us; speedup vs baseline: 1.0139x; 1.0139x over previous
//
#include <hip/hip_runtime.h>
#include <hip/hip_bf16.h>

// Fused Conv3d(3->16,k=3,valid) + conv_b + ReLU + maxpool2x2x2
// + spatial mean(fp32) + /2 + bias + channel-sum  ->  out[32] fp32.
// Inputs are FLOAT32 (harness materializes reference fp16 as f32).
//
// R6: two-pass im2col to halve LDS (54.3 -> ~33 KB) and restore 4 blocks/CU
// (32 waves/CU, the wave-slot ceiling). dh pool is a running max in regs, so
// slabs dd=0 (pass 0) and dd=1 (pass 1) reuse the same xs buffer.
//   Phase 1: coalesced float4 global loads (3/thread) -> v_cvt_pk_bf16_f32
//            -> raw bf16 LDS tile [3ci][4dl][4hl][128w] (12,288 B).
//   Phase 2 (per pass): im2col cols from raw LDS; thread = (col, tap-half),
//            16/11 ds_read_u16 (2-way/broadcast banking) -> 2x ds_write_b128
//            into xs[hh][w][tap] (stride 80 B, 16B-aligned).
//   Phase 3 (per pass, verified): mfma_f32_16x16x32_bf16, A=weights(regs),
//            B=im2col cols, kw via 3 shifted MFMAs; D: col=lane&15=w,
//            row=q*4+r=channel. Pool closes in-register; wave-reduce; atomic.

typedef __attribute__((ext_vector_type(8))) short short8;
typedef __attribute__((ext_vector_type(4))) float floatx4;
typedef __attribute__((ext_vector_type(2))) unsigned uint2v;

__device__ __forceinline__ short f2bf(float f) {
    // fp32 -> bf16 bits, RNE (finite inputs); used only for the 24 weight cvts
    unsigned u = __builtin_bit_cast(unsigned, f);
    unsigned r = (u + 0x7FFFu + ((u >> 16) & 1u)) >> 16;
    return (short)r;
}

__device__ __forceinline__ unsigned pkbf2(float a, float b) {
    __hip_bfloat162 h = __float22bfloat162_rn(float2{a, b});  // v_cvt_pk_bf16_f32
    unsigned r;
    __builtin_memcpy(&r, &h, 4);
    return r;
}

#define TAPS_PAD 40   // shorts per im2col column (80 B: 16B-aligned, bank-clean)
#define NCOL 130      // cols 0..127 staged, 128..129 zeroed once (never rewritten)

__global__ __launch_bounds__(512) void fused_conv_pool_reduce(
    const float* __restrict__ xg,    // f32 [32][3][32][128][128]
    const float* __restrict__ wg,    // f32 [16][3][3][3][3]
    const float* __restrict__ cbg,   // f32 [16]
    const float* __restrict__ biasg, // f32 [16]
    float* __restrict__ out)         // f32 [32]
{
    __shared__ __align__(16) unsigned rawu[3072];          // bf16 [3][4][4][128], 12,288 B
    __shared__ __align__(16) short xs[2][NCOL][TAPS_PAD];  // 20,800 B
    __shared__ float wsums[8];

    const int hp  = blockIdx.x;   // 0..62
    const int dp  = blockIdx.y;   // 0..14
    const int b   = blockIdx.z;   // 0..31
    const int tid = threadIdx.x;  // 0..511
    const int lane = tid & 63;
    const int wv   = tid >> 6;

    const int m = lane & 15;      // A-operand row (output channel)
    const int q = lane >> 4;      // K-quad

    // ---- A fragments (weights): A[m][k=q*8+j], one per kw ----
    short8 afrag[3];
    #pragma unroll
    for (int kw = 0; kw < 3; ++kw) {
        #pragma unroll
        for (int j = 0; j < 8; ++j) {
            const int k = q * 8 + j;
            afrag[kw][j] = (k < 27) ? f2bf(wg[m * 81 + k * 3 + kw]) : (short)0;
        }
    }

    // ---- zero im2col pad columns 128..129 (read-only; survive both passes) ----
    if (tid < 160) {
        const int hz  = tid / 80;
        const int rem = tid % 80;
        xs[hz][128 + rem / 40][rem % 40] = 0;
    }

    // ---- phase 1: raw stage, coalesced float4 + packed cvt ----
    {
        const int w4 = tid & 31, hr = (tid >> 5) & 3, dr = (tid >> 7) & 3;
        const float* src = xg + ((size_t)(b * 3) * 32 + 2 * dp + dr) * 16384
                              + (2 * hp + hr) * 128 + w4 * 4;
        const int fo = (dr * 128 + hr * 32 + w4) * 2;   // dword offset within ci slab
        #pragma unroll
        for (int ci = 0; ci < 3; ++ci) {
            const floatx4 v = *(const floatx4*)(src + (size_t)ci * 524288);
            uint2v pk; pk[0] = pkbf2(v[0], v[1]); pk[1] = pkbf2(v[2], v[3]);
            *(uint2v*)&rawu[fo + ci * 1024] = pk;       // ds_write_b64
        }
    }
    __syncthreads();

    const int n  = lane & 15;     // w position within tile (N = D col)
    const int w0 = wv * 16;
    floatx4 mx = {-3.0e38f, -3.0e38f, -3.0e38f, -3.0e38f};

    #pragma unroll
    for (int pass = 0; pass < 2; ++pass) {   // pass = dd (pool-d half)
        // ---- phase 2: build xs[hh][w] for dd = pass; thread = (col, tap-half) ----
        {
            const int colid = tid >> 1;           // 0..255
            const int hh = colid >> 7, w = colid & 127;
            const int half = tid & 1;             // taps 0..15 / 16..31
            const unsigned short* raws = (const unsigned short*)rawu;
            const unsigned short* base = raws + (pass) * 512 + hh * 128 + w;
            short* col = &xs[hh][w][half * 16];
            #pragma unroll
            for (int blk = 0; blk < 2; ++blk) {
                short8 pk;
                #pragma unroll
                for (int j = 0; j < 8; ++j) {
                    const int t = half * 16 + blk * 8 + j;          // tap index
                    if (t < 27) {
                        const int ci = t / 9, kd = (t % 9) / 3, kh = t % 3;
                        pk[j] = (short)base[ci * 2048 + kd * 512 + kh * 128];
                    } else {
                        pk[j] = 0;                                  // K pad 27..31
                    }
                }
                *(short8*)(col + blk * 8) = pk;                     // ds_write_b128
            }
        }
        __syncthreads();

        // ---- phase 3: MFMA over the 2 resident hh slabs, pool in-register ----
        #pragma unroll
        for (int dhl = 0; dhl < 2; ++dhl) {
            floatx4 acc = {0.f, 0.f, 0.f, 0.f};
            #pragma unroll
            for (int kw = 0; kw < 3; ++kw) {
                const short8 bfr = *(const short8*)(&xs[dhl][w0 + n + kw][q * 8]);
                acc = __builtin_amdgcn_mfma_f32_16x16x32_bf16(afrag[kw], bfr, acc, 0, 0, 0);
            }
            #pragma unroll
            for (int r = 0; r < 4; ++r) mx[r] = fmaxf(mx[r], acc[r]);  // pool d,h
        }
        __syncthreads();   // WAR guard before pass 1 rebuilds xs
    }

    // D row (channel) = q*4 + r; relu(max + conv_b[ch]) then w-pair pool
    float vsum = 0.f;
    #pragma unroll
    for (int r = 0; r < 4; ++r) {
        const float cb = cbg[q * 4 + r];
        float v = fmaxf(mx[r] + cb, 0.f);
        float o = __shfl_xor(v, 1, 64);
        vsum += fmaxf(v, o);
    }
    const bool ok = ((lane & 1) == 0) && (w0 + (n & 14) <= 124);  // conv W = 126
    float s = ok ? vsum : 0.f;
    #pragma unroll
    for (int off = 1; off < 64; off <<= 1) s += __shfl_xor(s, off, 64);

    if (lane == 0) wsums[wv] = s;
    __syncthreads();
    if (tid == 0) {
        float bs = 0.f;
        #pragma unroll
        for (int i = 0; i < 8; ++i) bs += wsums[i];
        float add = bs * (1.0f / 119070.0f);   // /(15*63*63)/2
        if (hp == 0 && dp == 0) {              // fold bias-sum init (out memset to 0)
            #pragma unroll
            for (int cc = 0; cc < 16; ++cc) add += biasg[cc];
        }
        atomicAdd(&out[b], add);
    }
}

extern "C" void kernel_launch(void* const* d_in, const int* in_sizes, int n_in,
                              void* d_out, int out_size, void* d_ws, size_t ws_size,
                              hipStream_t stream) {
    const float* x      = (const float*)d_in[0];
    const float* conv_w = (const float*)d_in[1];
    const float* conv_b = (const float*)d_in[2];
    const float* bias   = (const float*)d_in[3];
    float* out = (float*)d_out;

    (void)hipMemsetAsync(out, 0, 32 * sizeof(float), stream);  // graph-capturable
    dim3 grid(63, 15, 32);  // (hp, dp, b)
    fused_conv_pool_reduce<<<grid, 512, 0, stream>>>(x, conv_w, conv_b, bias, out);
}

// Round 7
// 583.865 us; speedup vs baseline: 1.0712x; 1.0566x over previous
//
#include <hip/hip_runtime.h>
#include <hip/hip_bf16.h>

// Fused Conv3d(3->16,k=3,valid) + conv_b + ReLU + maxpool2x2x2
// + spatial mean(fp32) + /2 + bias + channel-sum  ->  out[32] fp32.
// Inputs are FLOAT32 (harness materializes reference fp16 as f32).
//
// R7: hoist the A-fragment (weights) build into an init kernel -> d_ws table
// [kw][lane][j] bf16 (3 KB). Main kernel loads afrag as 3x dwordx4 coalesced
// (kills ~170 VALU/wave of per-block f2bf + scattered loads = 55% of VALU).
// Init kernel also writes out[b] = sum(bias)  -> memset launch dropped.
//   Phase 1: coalesced float4 global loads (3/thread) -> v_cvt_pk_bf16_f32
//            -> raw bf16 LDS tile [3ci][4dl][4hl][128w] (12,288 B).
//   Phase 2 (per dd pass): im2col cols from raw LDS; thread = (tap-half, col),
//            half wave-uniform -> broadcast-clean u16 reads; 2x ds_write_b128
//            into xs[hh][w][tap] (stride 80 B).
//   Phase 3 (verified): mfma_f32_16x16x32_bf16; D: col=lane&15=w,
//            row=q*4+r=channel. 2x2x2 pool in-register; wave-reduce; atomic.

typedef __attribute__((ext_vector_type(8))) short short8;
typedef __attribute__((ext_vector_type(4))) float floatx4;
typedef __attribute__((ext_vector_type(2))) unsigned uint2v;

__device__ __forceinline__ short f2bf(float f) {
    unsigned u = __builtin_bit_cast(unsigned, f);
    unsigned r = (u + 0x7FFFu + ((u >> 16) & 1u)) >> 16;
    return (short)r;
}

__device__ __forceinline__ unsigned pkbf2(float a, float b) {
    __hip_bfloat162 h = __float22bfloat162_rn(float2{a, b});  // v_cvt_pk_bf16_f32
    unsigned r;
    __builtin_memcpy(&r, &h, 4);
    return r;
}

#define TAPS_PAD 40   // shorts per im2col column (80 B: 16B-aligned, bank-clean)
#define NCOL 130      // cols 0..127 staged, 128..129 zeroed once

// ---- init: weight-frag table (3*64 lanes * 8 taps bf16) + out = bias sums ----
__global__ void init_kernel(const float* __restrict__ wg,
                            const float* __restrict__ biasg,
                            short* __restrict__ wtab,   // d_ws: [3][64][8] bf16
                            float* __restrict__ out)    // [32]
{
    const int tid = threadIdx.x;          // 0..191
    const int kw = tid >> 6, lane = tid & 63;
    const int m = lane & 15, q = lane >> 4;
    #pragma unroll
    for (int j = 0; j < 8; ++j) {
        const int k = q * 8 + j;
        wtab[tid * 8 + j] = (k < 27) ? f2bf(wg[m * 81 + k * 3 + kw]) : (short)0;
    }
    if (tid < 32) {
        float s = 0.f;
        #pragma unroll
        for (int cc = 0; cc < 16; ++cc) s += biasg[cc];
        out[tid] = s;   // conv blocks atomicAdd on top
    }
}

__global__ __launch_bounds__(512) void fused_conv_pool_reduce(
    const float* __restrict__ xg,    // f32 [32][3][32][128][128]
    const short* __restrict__ wtab,  // bf16 table [3][64][8] in d_ws
    const float* __restrict__ cbg,   // f32 [16]
    float* __restrict__ out)         // f32 [32]
{
    __shared__ __align__(16) unsigned rawu[3072];          // bf16 [3][4][4][128], 12,288 B
    __shared__ __align__(16) short xs[2][NCOL][TAPS_PAD];  // 20,800 B
    __shared__ float wsums[8];

    const int hp  = blockIdx.x;   // 0..62
    const int dp  = blockIdx.y;   // 0..14
    const int b   = blockIdx.z;   // 0..31
    const int tid = threadIdx.x;  // 0..511
    const int lane = tid & 63;
    const int wv   = tid >> 6;

    const int q = lane >> 4;      // K-quad

    // ---- A fragments: 3 coalesced 16B loads from the precomputed table ----
    short8 afrag[3];
    {
        const short8* wt = (const short8*)wtab;
        #pragma unroll
        for (int kw = 0; kw < 3; ++kw) afrag[kw] = wt[kw * 64 + lane];
    }

    // ---- zero im2col pad columns 128..129 (read-only; survive both passes) ----
    if (tid < 160) {
        const int hz  = tid / 80;
        const int rem = tid % 80;
        xs[hz][128 + rem / 40][rem % 40] = 0;
    }

    // ---- phase 1: raw stage, coalesced float4 + packed cvt ----
    {
        const int w4 = tid & 31, hr = (tid >> 5) & 3, dr = (tid >> 7) & 3;
        const float* src = xg + ((size_t)(b * 3) * 32 + 2 * dp + dr) * 16384
                              + (2 * hp + hr) * 128 + w4 * 4;
        const int fo = (dr * 128 + hr * 32 + w4) * 2;   // dword offset within ci slab
        #pragma unroll
        for (int ci = 0; ci < 3; ++ci) {
            const floatx4 v = *(const floatx4*)(src + (size_t)ci * 524288);
            uint2v pk; pk[0] = pkbf2(v[0], v[1]); pk[1] = pkbf2(v[2], v[3]);
            *(uint2v*)&rawu[fo + ci * 1024] = pk;       // ds_write_b64
        }
    }
    __syncthreads();

    const int n  = lane & 15;     // w position within tile (N = D col)
    const int w0 = wv * 16;
    floatx4 mx = {-3.0e38f, -3.0e38f, -3.0e38f, -3.0e38f};

    #pragma unroll
    for (int pass = 0; pass < 2; ++pass) {   // pass = dd (pool-d half)
        // ---- phase 2: build xs[hh][w] for dd = pass ----
        // thread = (half = tid>>8 wave-uniform, col = tid&255)
        {
            const int colid = tid & 255;
            const int hh = colid >> 7, w = colid & 127;
            const int half = tid >> 8;            // taps 0..15 / 16..31
            const unsigned short* raws = (const unsigned short*)rawu;
            const unsigned short* base = raws + pass * 512 + hh * 128 + w;
            short* col = &xs[hh][w][half * 16];
            #pragma unroll
            for (int blk = 0; blk < 2; ++blk) {
                short8 pk;
                #pragma unroll
                for (int j = 0; j < 8; ++j) {
                    const int t = half * 16 + blk * 8 + j;          // tap index
                    if (t < 27) {
                        const int ci = t / 9, kd = (t % 9) / 3, kh = t % 3;
                        pk[j] = (short)base[ci * 2048 + kd * 512 + kh * 128];
                    } else {
                        pk[j] = 0;                                  // K pad 27..31
                    }
                }
                *(short8*)(col + blk * 8) = pk;                     // ds_write_b128
            }
        }
        __syncthreads();

        // ---- phase 3: MFMA over the 2 resident hh slabs, pool in-register ----
        #pragma unroll
        for (int dhl = 0; dhl < 2; ++dhl) {
            floatx4 acc = {0.f, 0.f, 0.f, 0.f};
            #pragma unroll
            for (int kw = 0; kw < 3; ++kw) {
                const short8 bfr = *(const short8*)(&xs[dhl][w0 + n + kw][q * 8]);
                acc = __builtin_amdgcn_mfma_f32_16x16x32_bf16(afrag[kw], bfr, acc, 0, 0, 0);
            }
            #pragma unroll
            for (int r = 0; r < 4; ++r) mx[r] = fmaxf(mx[r], acc[r]);  // pool d,h
        }
        __syncthreads();   // WAR guard before pass 1 rebuilds xs
    }

    // D row (channel) = q*4 + r; relu(max + conv_b[ch]) then w-pair pool
    float vsum = 0.f;
    #pragma unroll
    for (int r = 0; r < 4; ++r) {
        const float cb = cbg[q * 4 + r];
        float v = fmaxf(mx[r] + cb, 0.f);
        float o = __shfl_xor(v, 1, 64);
        vsum += fmaxf(v, o);
    }
    const bool ok = ((lane & 1) == 0) && (w0 + (n & 14) <= 124);  // conv W = 126
    float s = ok ? vsum : 0.f;
    #pragma unroll
    for (int off = 1; off < 64; off <<= 1) s += __shfl_xor(s, off, 64);

    if (lane == 0) wsums[wv] = s;
    __syncthreads();
    if (tid == 0) {
        float bs = 0.f;
        #pragma unroll
        for (int i = 0; i < 8; ++i) bs += wsums[i];
        atomicAdd(&out[b], bs * (1.0f / 119070.0f));   // /(15*63*63)/2
    }
}

extern "C" void kernel_launch(void* const* d_in, const int* in_sizes, int n_in,
                              void* d_out, int out_size, void* d_ws, size_t ws_size,
                              hipStream_t stream) {
    const float* x      = (const float*)d_in[0];
    const float* conv_w = (const float*)d_in[1];
    const float* conv_b = (const float*)d_in[2];
    const float* bias   = (const float*)d_in[3];
    float* out = (float*)d_out;
    short* wtab = (short*)d_ws;   // 3*64*8 bf16 = 3 KB

    init_kernel<<<1, 192, 0, stream>>>(conv_w, bias, wtab, out);
    dim3 grid(63, 15, 32);  // (hp, dp, b)
    fused_conv_pool_reduce<<<grid, 512, 0, stream>>>(x, wtab, conv_b, out);
}